// Round 1
// baseline (194.699 us; speedup 1.0000x reference)
//
#include <hip/hip_runtime.h>
#include <math.h>

// LFQ (lookup-free quantization) fused kernel set for MI355X.
//
// Shapes: z [4,14,32,32] fp32, codebook [16384,14] (= sign bits, not needed),
// codebook_used [65536] int32 ring buffer.
// Outputs (concatenated float32 in d_out):
//   [0,57344)   quantized = sign(z), same b,d,h,w layout as z
//   [57344]     commit_loss     = 0.25 * mean((z - sign(z))^2)
//   [57345]     entropy_aux_loss= 0.1 * (sample_entropy - avg_entropy)
//   [57346]     codebook_usage  = (#bins with count>0) / 16384
//   [57347,...) idx_flat [4096] as float
//
// Math: scaled_j = 200 * sum_k (+-z_k)  (T=0.01, logits=2*dot).
// softmax factorizes over bits -> p_j = EA[j&127] * EB[j>>7] with
//   EA[jlo] = exp(200*(A[jlo]-maxA)),  EB[jhi] = exp(200*(B[jhi]-maxB) - logZrel)
//   logZrel = sum_k log1p(exp(-400*|z_k|)),  both factors <= 1 (no overflow).
// avg_probs = (1/4096) * sum_t outer(EB_t, EA_t)  -> 128x128x4096 fp32 GEMM.
// sample_entropy = mean_t sum_k [log1p(e^-u) + u*e^-u/(1+e^-u)], u=400|z_k|.

static constexpr int NE       = 16384;
static constexpr int EDIM     = 14;
static constexpr int NTOK     = 4096;    // 4 * 32 * 32
static constexpr int ZELEMS   = 57344;   // 4 * 14 * 1024
static constexpr int UBUF     = 65536;

// ws layout (bytes)
static constexpr size_t EA_OFF     = 0;                 // 4096*128 fp32 = 2 MB
static constexpr size_t EB_OFF     = 2u << 20;          // 2 MB
static constexpr size_t AVG_OFF    = 4u << 20;          // 16384 fp32 (zeroed)
static constexpr size_t FLAGS_OFF  = (4u << 20) + 65536;    // 16384 int (zeroed)
static constexpr size_t COMMIT_OFF = (4u << 20) + 131072;   // 4096 fp32
static constexpr size_t HP_OFF     = (4u << 20) + 131072 + 16384; // 4096 fp32

// ---------------- Kernel A: per-token tables + idx + quantized + partials ---
__global__ __launch_bounds__(128) void token_kernel(
    const float* __restrict__ z, float* __restrict__ out,
    float* __restrict__ EA, float* __restrict__ EB,
    int* __restrict__ flags, float* __restrict__ commit_p,
    float* __restrict__ H_p)
{
    const int t   = blockIdx.x;        // token id = b*1024 + pos
    const int b   = t >> 10;
    const int pos = t & 1023;
    const int lane = threadIdx.x;      // 0..127 = table entry

    __shared__ float sz[EDIM];
    if (lane < EDIM) sz[lane] = z[b * 14336 + lane * 1024 + pos];
    __syncthreads();

    // subset sums for this lane's 7-bit pattern (low half + high half)
    float A = 0.f, Bv = 0.f, maxA = 0.f, maxB = 0.f, lzr = 0.f;
    #pragma unroll
    for (int k = 0; k < 7; ++k) {
        float zl = sz[k], zh = sz[k + 7];
        float al = fabsf(zl), ah = fabsf(zh);
        A  += ((lane >> k) & 1) ? zl : -zl;
        Bv += ((lane >> k) & 1) ? zh : -zh;
        maxA += al;
        maxB += ah;
        lzr += log1pf(__expf(-400.f * al)) + log1pf(__expf(-400.f * ah));
    }
    EA[t * 128 + lane] = __expf(200.f * (A  - maxA));
    EB[t * 128 + lane] = __expf(200.f * (Bv - maxB) - lzr);

    // quantized = sign(z), same layout as z
    if (lane < EDIM)
        out[b * 14336 + lane * 1024 + pos] = sz[lane] > 0.f ? 1.f : -1.f;

    if (lane == 0) {
        int idx = 0;
        float c = 0.f, H = 0.f;
        #pragma unroll
        for (int k = 0; k < EDIM; ++k) {
            float zv = sz[k];
            int bit = zv > 0.f;
            idx |= bit << k;
            float q = bit ? 1.f : -1.f;
            float d = zv - q;
            c += d * d;
            float u = 400.f * fabsf(zv);
            float e = __expf(-u);
            H += log1pf(e) + u * e / (1.f + e);   // binary entropy, exact
        }
        out[ZELEMS + 3 + t] = (float)idx;
        flags[idx] = 1;                // plain store: all writers store 1
        commit_p[t] = c;
        H_p[t] = H;
    }
}

// ---------------- Kernel D: ring-buffer survivors set usage flags ----------
__global__ void ring_kernel(const int* __restrict__ used, int* __restrict__ flags)
{
    int i = blockIdx.x * blockDim.x + threadIdx.x;
    if (i < UBUF - NTOK) {
        int v = used[NTOK + i] & (NE - 1);
        flags[v] = 1;
    }
}

// ---------------- Kernel B: avg_probs accumulation as 128x128x4096 GEMM ----
// 64 blocks x 64 tokens; each block computes a full 128x128 partial C and
// atomically adds it (each address hit by exactly 64 blocks).
__global__ __launch_bounds__(256) void gemm_kernel(
    const float* __restrict__ EA, const float* __restrict__ EB,
    float* __restrict__ avg_sum)
{
    __shared__ float sEA[1024], sEB[1024];   // 8 tokens per stage
    const int t0 = blockIdx.x * 64;
    const int tx = threadIdx.x & 15, ty = threadIdx.x >> 4;
    const int jlo0 = tx * 8, jhi0 = ty * 8;

    float acc[8][8];
    #pragma unroll
    for (int j = 0; j < 8; ++j)
        #pragma unroll
        for (int i = 0; i < 8; ++i) acc[j][i] = 0.f;

    for (int batch = 0; batch < 8; ++batch) {
        __syncthreads();
        const int tb = t0 + batch * 8;
        for (int i = threadIdx.x; i < 1024; i += 256) {
            sEA[i] = EA[tb * 128 + i];
            sEB[i] = EB[tb * 128 + i];
        }
        __syncthreads();
        #pragma unroll
        for (int tt = 0; tt < 8; ++tt) {
            float ea[8], eb[8];
            #pragma unroll
            for (int i = 0; i < 8; ++i) {
                ea[i] = sEA[tt * 128 + jlo0 + i];
                eb[i] = sEB[tt * 128 + jhi0 + i];
            }
            #pragma unroll
            for (int j = 0; j < 8; ++j)
                #pragma unroll
                for (int i = 0; i < 8; ++i)
                    acc[j][i] += eb[j] * ea[i];
        }
    }
    #pragma unroll
    for (int j = 0; j < 8; ++j)
        #pragma unroll
        for (int i = 0; i < 8; ++i)
            atomicAdd(&avg_sum[(jhi0 + j) * 128 + (jlo0 + i)], acc[j][i]);
}

// ---------------- Kernel C: finalize scalars -------------------------------
__global__ __launch_bounds__(256) void finalize_kernel(
    const float* __restrict__ avg_sum, const int* __restrict__ flags,
    const float* __restrict__ commit_p, const float* __restrict__ H_p,
    float* __restrict__ out)
{
    const int tid = threadIdx.x;
    float s_ent = 0.f, s_cnt = 0.f, s_c = 0.f, s_h = 0.f;
    for (int j = tid; j < NE; j += 256) {
        float a = avg_sum[j] * (1.0f / 4096.0f);
        s_ent += a * logf(a + 1e-5f);
        s_cnt += (flags[j] != 0) ? 1.f : 0.f;
    }
    for (int t = tid; t < NTOK; t += 256) {
        s_c += commit_p[t];
        s_h += H_p[t];
    }
    __shared__ float red[4][256];
    red[0][tid] = s_ent; red[1][tid] = s_cnt; red[2][tid] = s_c; red[3][tid] = s_h;
    __syncthreads();
    for (int off = 128; off > 0; off >>= 1) {
        if (tid < off) {
            #pragma unroll
            for (int q = 0; q < 4; ++q) red[q][tid] += red[q][tid + off];
        }
        __syncthreads();
    }
    if (tid == 0) {
        float avg_entropy    = -red[0][0];
        float sample_entropy = red[3][0] * (1.0f / 4096.0f);
        out[ZELEMS + 0] = 0.25f * red[2][0] * (1.0f / (float)ZELEMS);
        out[ZELEMS + 1] = 0.1f * (sample_entropy - avg_entropy);
        out[ZELEMS + 2] = red[1][0] * (1.0f / (float)NE);
    }
}

extern "C" void kernel_launch(void* const* d_in, const int* in_sizes, int n_in,
                              void* d_out, int out_size, void* d_ws, size_t ws_size,
                              hipStream_t stream)
{
    const float* z    = (const float*)d_in[0];
    const int*   used = (const int*)d_in[2];   // d_in[1] codebook: implied by bit math
    float* out = (float*)d_out;
    char*  ws  = (char*)d_ws;

    float* EA       = (float*)(ws + EA_OFF);
    float* EB       = (float*)(ws + EB_OFF);
    float* avg_sum  = (float*)(ws + AVG_OFF);
    int*   flags    = (int*)  (ws + FLAGS_OFF);
    float* commit_p = (float*)(ws + COMMIT_OFF);
    float* H_p      = (float*)(ws + HP_OFF);

    // zero avg_sum + flags (ws is re-poisoned to 0xAA before every launch)
    hipMemsetAsync(ws + AVG_OFF, 0, 131072, stream);

    token_kernel<<<NTOK, 128, 0, stream>>>(z, out, EA, EB, flags, commit_p, H_p);
    ring_kernel<<<(UBUF - NTOK + 255) / 256, 256, 0, stream>>>(used, flags);
    gemm_kernel<<<64, 256, 0, stream>>>(EA, EB, avg_sum);
    finalize_kernel<<<1, 256, 0, stream>>>(avg_sum, flags, commit_p, H_p, out);
}

// Round 2
// 95.793 us; speedup vs baseline: 2.0325x; 2.0325x over previous
//
#include <hip/hip_runtime.h>
#include <math.h>

// LFQ fused kernels, round 2: atomic-free avg_probs via per-block partials,
// transcendental-free table construction (EA[j] = prod of e_k over mismatched
// bits, e_k = exp(-400|z_k|)), everything fused into 4 dispatches.
//
// Outputs (float32, concatenated):
//   [0,57344)  quantized = sign(z)   (b d h w layout)
//   [57344]    commit_loss
//   [57345]    entropy_aux_loss
//   [57346]    codebook_usage
//   [57347..]  idx_flat [4096]

static constexpr int NE     = 16384;
static constexpr int EDIM   = 14;
static constexpr int NTOK   = 4096;
static constexpr int ZELEMS = 57344;
static constexpr int UBUF   = 65536;
static constexpr int RING_ELEMS  = UBUF - NTOK;        // 61440
static constexpr int RING_BLOCKS = RING_ELEMS / 256;   // 240

// ---------------------------------------------------------------------------
// K1: fused per-token math + table build + rank-1-sum GEMM partial + ring.
// Blocks [0,P): TPB=4096/P tokens each. Blocks [P, P+240): ring-buffer flags.
// ---------------------------------------------------------------------------
__global__ __launch_bounds__(256) void fused_kernel(
    const float* __restrict__ z, const int* __restrict__ used,
    float* __restrict__ out, float* __restrict__ partial,
    int* __restrict__ flags, float* __restrict__ blkC, float* __restrict__ blkH,
    int P, int tpb_sh)
{
    extern __shared__ float dynsm[];          // sEA[TPB*128] ++ sEB[TPB*128]
    __shared__ float se[64 * EDIM];           // e_k per (token, bit)
    __shared__ float sC[64], sH[64], sLzr[64], sEsc[64];
    __shared__ int   sBits[64];

    const int tid = threadIdx.x;
    const int bid = blockIdx.x;

    if (bid >= P) {                           // ring-buffer survivor flags
        int i = (bid - P) * 256 + tid;
        if (i < RING_ELEMS) flags[used[NTOK + i] & (NE - 1)] = 1;
        return;
    }

    const int TPB = 1 << tpb_sh;              // tokens per block: 16/32/64
    float* sEA = dynsm;
    float* sEB = dynsm + TPB * 128;

    if (tid < TPB) { sC[tid] = 0.f; sH[tid] = 0.f; sLzr[tid] = 0.f; sBits[tid] = 0; }
    __syncthreads();

    const int t0    = bid << tpb_sh;          // first token of block
    const int b     = t0 >> 10;
    const int pos0  = t0 & 1023;
    const int zbase = b * 14336 + pos0;

    // ---- Stage A: per (bit k, token tt) pair --------------------------------
    for (int p = tid; p < (EDIM << tpb_sh); p += 256) {
        const int k  = p >> tpb_sh;
        const int tt = p & (TPB - 1);
        const int ga = zbase + k * 1024 + tt; // coalesced (tt fastest)
        float zv  = z[ga];
        int   bit = zv > 0.f;
        float q   = bit ? 1.f : -1.f;
        out[ga] = q;                          // quantized = sign(z)
        float d  = zv - q;
        float az = fabsf(zv);
        float u  = 400.f * az;
        float e  = __expf(-u);                // e_k
        float l1 = log1pf(e);
        se[tt * EDIM + k] = e;
        atomicAdd(&sC[tt], d * d);
        atomicAdd(&sH[tt], l1 + u * e / (1.f + e));  // exact binary entropy
        atomicAdd(&sLzr[tt], l1);             // log(Z) - s_max
        if (bit) atomicOr(&sBits[tt], 1 << k);
    }
    __syncthreads();

    if (tid < TPB) {
        sEsc[tid] = __expf(-sLzr[tid]);       // normalization factor
        int idx = sBits[tid];
        out[ZELEMS + 3 + t0 + tid] = (float)idx;
        flags[idx] = 1;
    }
    if (tid == 0) {                           // block partials for commit/H
        float c = 0.f, h = 0.f;
        for (int i = 0; i < TPB; ++i) { c += sC[i]; h += sH[i]; }
        blkC[bid] = c; blkH[bid] = h;
    }
    __syncthreads();

    // ---- Stage B: build EA/EB tables (no transcendentals) -------------------
    {
        const int chunk = TPB / 2;            // (TPB*128)/256 entries/thread
        const int i0 = tid * chunk;
        const int tt = i0 >> 7;
        const int j0 = i0 & 127;
        float ee[EDIM];
        #pragma unroll
        for (int k = 0; k < EDIM; ++k) ee[k] = se[tt * EDIM + k];
        const int bits = sBits[tt];
        const float esc = sEsc[tt];
        for (int c = 0; c < chunk; ++c) {
            const int j = j0 + c;
            float pa = 1.f, pb = 1.f;
            #pragma unroll
            for (int k = 0; k < 7; ++k) {
                int jb = (j >> k) & 1;
                pa *= (jb != ((bits >> k) & 1))       ? ee[k]     : 1.f;
                pb *= (jb != ((bits >> (k + 7)) & 1)) ? ee[k + 7] : 1.f;
            }
            sEA[tt * 128 + j] = pa;
            sEB[tt * 128 + j] = pb * esc;
        }
    }
    __syncthreads();

    // ---- Stage C: sum of outer products over TPB tokens ---------------------
    const int tx = tid & 15, ty = tid >> 4;
    const int jlo0 = tx * 8, jhi0 = ty * 8;
    float acc[8][8] = {};
    for (int tt = 0; tt < TPB; ++tt) {
        float4 a0 = *(const float4*)&sEA[tt * 128 + jlo0];
        float4 a1 = *(const float4*)&sEA[tt * 128 + jlo0 + 4];
        float4 b0 = *(const float4*)&sEB[tt * 128 + jhi0];
        float4 b1 = *(const float4*)&sEB[tt * 128 + jhi0 + 4];
        float ea[8] = {a0.x, a0.y, a0.z, a0.w, a1.x, a1.y, a1.z, a1.w};
        float eb[8] = {b0.x, b0.y, b0.z, b0.w, b1.x, b1.y, b1.z, b1.w};
        #pragma unroll
        for (int j = 0; j < 8; ++j)
            #pragma unroll
            for (int i = 0; i < 8; ++i) acc[j][i] += eb[j] * ea[i];
    }

    // ---- Stage D: plain coalesced store of this block's 128x128 partial -----
    float* dst = partial + bid * 16384;
    #pragma unroll
    for (int j = 0; j < 8; ++j) {
        *(float4*)&dst[(jhi0 + j) * 128 + jlo0] =
            make_float4(acc[j][0], acc[j][1], acc[j][2], acc[j][3]);
        *(float4*)&dst[(jhi0 + j) * 128 + jlo0 + 4] =
            make_float4(acc[j][4], acc[j][5], acc[j][6], acc[j][7]);
    }
}

// ---------------------------------------------------------------------------
// K2: reduce P partials per codebook entry; fuse entropy + usage count +
// commit/H partial reduction. 64 blocks x 256 threads (one thread per entry).
// ---------------------------------------------------------------------------
__global__ __launch_bounds__(256) void reduce_kernel(
    const float* __restrict__ partial, const int* __restrict__ flags,
    const float* __restrict__ blkC, const float* __restrict__ blkH,
    float* __restrict__ acc, int P)
{
    const int tid = threadIdx.x;
    const int j = blockIdx.x * 256 + tid;
    float s0 = 0.f, s1 = 0.f, s2 = 0.f, s3 = 0.f;
    for (int p = 0; p < P; p += 4) {          // P divisible by 4
        s0 += partial[(p + 0) * 16384 + j];
        s1 += partial[(p + 1) * 16384 + j];
        s2 += partial[(p + 2) * 16384 + j];
        s3 += partial[(p + 3) * 16384 + j];
    }
    float a = (s0 + s1 + s2 + s3) * (1.0f / 4096.0f);
    float v_ent = a * logf(a + 1e-5f);
    float v_cnt = (flags[j] != 0) ? 1.f : 0.f;
    float v_c = 0.f, v_h = 0.f;
    if (blockIdx.x == 0 && tid < P) { v_c = blkC[tid]; v_h = blkH[tid]; }

    __shared__ float red[4][256];
    red[0][tid] = v_ent; red[1][tid] = v_cnt; red[2][tid] = v_c; red[3][tid] = v_h;
    __syncthreads();
    for (int off = 128; off > 0; off >>= 1) {
        if (tid < off) {
            #pragma unroll
            for (int q = 0; q < 4; ++q) red[q][tid] += red[q][tid + off];
        }
        __syncthreads();
    }
    if (tid == 0) {
        atomicAdd(&acc[0], red[0][0]);
        atomicAdd(&acc[1], red[1][0]);
        atomicAdd(&acc[2], red[2][0]);
        atomicAdd(&acc[3], red[3][0]);
    }
}

// ---------------------------------------------------------------------------
// K3: final 3 scalars.
// ---------------------------------------------------------------------------
__global__ void final_kernel(const float* __restrict__ acc, float* __restrict__ out)
{
    if (threadIdx.x == 0) {
        float avg_entropy    = -acc[0];
        float sample_entropy = acc[3] * (1.0f / 4096.0f);
        out[ZELEMS + 0] = 0.25f * acc[2] * (1.0f / (float)ZELEMS);
        out[ZELEMS + 1] = 0.1f * (sample_entropy - avg_entropy);
        out[ZELEMS + 2] = acc[1] * (1.0f / (float)NE);
    }
}

extern "C" void kernel_launch(void* const* d_in, const int* in_sizes, int n_in,
                              void* d_out, int out_size, void* d_ws, size_t ws_size,
                              hipStream_t stream)
{
    const float* z    = (const float*)d_in[0];
    const int*   used = (const int*)d_in[2];   // d_in[1] codebook unused (bit math)
    float* out = (float*)d_out;
    char*  ws  = (char*)d_ws;

    // adaptive partial count: more blocks if ws allows
    int P, tpb_sh;
    const size_t tail = 65536 + 16 + 2048;     // flags + acc + blkC/blkH
    if      (ws_size >= 256u * 65536 + tail) { P = 256; tpb_sh = 4; }
    else if (ws_size >= 128u * 65536 + tail) { P = 128; tpb_sh = 5; }
    else                                     { P = 64;  tpb_sh = 6; }

    float* partial = (float*)ws;
    int*   flags   = (int*)  (ws + (size_t)P * 65536);
    float* acc     = (float*)(ws + (size_t)P * 65536 + 65536);
    float* blkC    = (float*)(ws + (size_t)P * 65536 + 65536 + 16);
    float* blkH    = blkC + 256;

    // zero flags + acc (ws is poisoned 0xAA before every timed call)
    hipMemsetAsync(flags, 0, 65536 + 16, stream);

    const int TPB = 1 << tpb_sh;
    const size_t dyn = (size_t)TPB * 128 * 2 * sizeof(float);
    fused_kernel<<<P + RING_BLOCKS, 256, dyn, stream>>>(
        z, used, out, partial, flags, blkC, blkH, P, tpb_sh);
    reduce_kernel<<<64, 256, 0, stream>>>(partial, flags, blkC, blkH, acc, P);
    final_kernel<<<1, 64, 0, stream>>>(acc, out);
}